// Round 4
// baseline (566.300 us; speedup 1.0000x reference)
//
#include <hip/hip_runtime.h>

#define EPS 1e-5f
#define NTHR 256
#define NBLK 512

typedef __bf16 bf16x8 __attribute__((ext_vector_type(8)));
typedef float f32x16 __attribute__((ext_vector_type(16)));

// d_ws layout:
//   [0, N*32)        bf16 x in MFMA B-frag order: xb[(t*64+lane)*8 .. +8)
//   [N*32, +768)     stats: layer L at stats[L*64 + 0..63] (sum | sumsq)
//   [N*32+768, +4)   barrier counter
//
// 32x32x16 bf16 MFMA layouts (m74/m101-verified):
//   C/D: col=lane&31 (data row), row p=(reg&3)+8*(reg>>2)+4h, h=lane>>5
//   A/B: m|n=lane&31, k=8h+j
// Acc regs 0..7 / 8..15 feed the next layer's B-frag; next-layer weights use
// columns permuted by phi(K)=(j&3)+8*(j>>2)+4h+16*kh (involution). BN scale
// a>0 folds into next-layer weight columns; shift e=b-mu+be/a folds into the
// accumulator init. Phase k uses raw bias b_k until its stats exist.

__device__ __forceinline__ void gbarrier(unsigned* cnt, unsigned target, int tid) {
    __syncthreads();
    __threadfence();   // release: drain stores + L2 writeback (cross-XCD)
    if (tid == 0) {
        __hip_atomic_fetch_add(cnt, 1u, __ATOMIC_ACQ_REL, __HIP_MEMORY_SCOPE_AGENT);
        while (__hip_atomic_load(cnt, __ATOMIC_ACQUIRE, __HIP_MEMORY_SCOPE_AGENT) < target)
            __builtin_amdgcn_s_sleep(8);
    }
    __syncthreads();
    __threadfence();   // acquire: invalidate stale L1/L2 lines
}

__global__ __launch_bounds__(NTHR, 2) void k_all(
    const float* __restrict__ x, __bf16* __restrict__ xb,
    const float* __restrict__ W1, const float* __restrict__ b1,
    const float* __restrict__ g1, const float* __restrict__ be1,
    const float* __restrict__ W2, const float* __restrict__ b2,
    const float* __restrict__ g2, const float* __restrict__ be2,
    const float* __restrict__ W3, const float* __restrict__ b3,
    const float* __restrict__ g3, const float* __restrict__ be3,
    const float* __restrict__ W4, const float* __restrict__ b4,
    float* __restrict__ stats, unsigned* __restrict__ cnt,
    float* __restrict__ out, int N)
{
    __shared__ float s_a[32], s_e[32], s_b[64];

    const int tid  = threadIdx.x;
    const int lane = tid & 63;
    const int h    = lane >> 5;
    const int ml   = lane & 31;
    const float invN = 1.0f / (float)N;

    const int ntiles = N >> 5;
    const int nwaves = NBLK * (NTHR / 64);
    const int gwave  = blockIdx.x * (NTHR / 64) + (tid >> 6);

    float sums[16], sqs[16];

    auto zero_acc = [&]() {
        #pragma unroll
        for (int i = 0; i < 16; ++i) { sums[i] = 0.f; sqs[i] = 0.f; }
    };
    auto accum = [&](const f32x16& a) {
        #pragma unroll
        for (int i = 0; i < 16; ++i) { sums[i] += a[i]; sqs[i] = fmaf(a[i], a[i], sqs[i]); }
    };
    auto flush = [&](int L) {
        __syncthreads();
        if (tid < 64) s_b[tid] = 0.f;
        __syncthreads();
        #pragma unroll
        for (int i = 0; i < 16; ++i) {
            float s = sums[i], q = sqs[i];
            #pragma unroll
            for (int d = 1; d <= 16; d <<= 1) { s += __shfl_xor(s, d); q += __shfl_xor(q, d); }
            if (ml == 0) {
                int p = (i & 3) + 8 * (i >> 2) + 4 * h;
                atomicAdd(&s_b[p], s);
                atomicAdd(&s_b[32 + p], q);
            }
        }
        __syncthreads();
        if (tid < 64) atomicAdd(&stats[L * 64 + tid], s_b[tid]);
    };
    auto derive = [&](int L, const float* g, const float* be, const float* b) {
        if (tid < 32) {
            float su = __hip_atomic_load(&stats[L * 64 + tid], __ATOMIC_RELAXED, __HIP_MEMORY_SCOPE_AGENT);
            float sq = __hip_atomic_load(&stats[L * 64 + 32 + tid], __ATOMIC_RELAXED, __HIP_MEMORY_SCOPE_AGENT);
            float mu = su * invN;
            float v  = sq * invN - mu * mu;
            float a  = g[tid] * rsqrtf(v + EPS);
            s_a[tid] = a;
            s_e[tid] = b[tid] - mu + be[tid] / a;
        }
        __syncthreads();
    };
    auto run2 = [&](auto&& body) {
        int t = gwave;
        for (; t + nwaves < ntiles; t += 2 * nwaves) { body(t); body(t + nwaves); }
        if (t < ntiles) body(t);
    };
    auto loadxb = [&](int t) -> bf16x8 {
        return *(const bf16x8*)(xb + ((size_t)t * 64 + lane) * 8);
    };
    auto build_wf = [&](const float* W, bf16x8& f0, bf16x8& f1) {
        #pragma unroll
        for (int kh = 0; kh < 2; ++kh)
            #pragma unroll
            for (int j = 0; j < 8; ++j) {
                int pk = (j & 3) + 8 * (j >> 2) + 4 * h + 16 * kh;
                float v = W[ml * 32 + pk] * s_a[pk];
                if (kh == 0) f0[j] = (__bf16)v; else f1[j] = (__bf16)v;
            }
    };

    // ---------------- Phase 1: stream x -> xb, z1 stats ----------------
    bf16x8 w1f;
    {
        const float* p = W1 + ml * 16 + h * 8;
        #pragma unroll
        for (int j = 0; j < 8; ++j) w1f[j] = (__bf16)p[j];
    }
    f32x16 c1;
    #pragma unroll
    for (int i = 0; i < 16; ++i) c1[i] = b1[(i & 3) + 8 * (i >> 2) + 4 * h];

    zero_acc();
    run2([&](int t) {
        int row = (t << 5) + ml;
        const float4* xp = (const float4*)(x + (size_t)row * 16 + h * 8);
        float4 u0 = xp[0], u1 = xp[1];
        bf16x8 xf;
        xf[0] = (__bf16)u0.x; xf[1] = (__bf16)u0.y; xf[2] = (__bf16)u0.z; xf[3] = (__bf16)u0.w;
        xf[4] = (__bf16)u1.x; xf[5] = (__bf16)u1.y; xf[6] = (__bf16)u1.z; xf[7] = (__bf16)u1.w;
        *(bf16x8*)(xb + ((size_t)t * 64 + lane) * 8) = xf;
        f32x16 a1 = __builtin_amdgcn_mfma_f32_32x32x16_bf16(w1f, xf, c1, 0, 0, 0);
        accum(a1);
    });
    flush(0);
    gbarrier(cnt, NBLK, tid);
    derive(0, g1, be1, b1);

    bf16x8 w2f0, w2f1;
    build_wf(W2, w2f0, w2f1);
    f32x16 c2;
    #pragma unroll
    for (int i = 0; i < 16; ++i) {
        int p = (i & 3) + 8 * (i >> 2) + 4 * h;
        c1[i] = s_e[p];      // rebuild layer-1 init with BN fold
        c2[i] = b2[p];
    }

    // ---------------- Phase 2: z2 stats ----------------
    zero_acc();
    run2([&](int t) {
        bf16x8 xf = loadxb(t);
        f32x16 a1 = __builtin_amdgcn_mfma_f32_32x32x16_bf16(w1f, xf, c1, 0, 0, 0);
        bf16x8 qa, qb;
        #pragma unroll
        for (int j = 0; j < 8; ++j) {
            qa[j] = (__bf16)fmaxf(a1[j], 0.f);
            qb[j] = (__bf16)fmaxf(a1[8 + j], 0.f);
        }
        f32x16 a2 = __builtin_amdgcn_mfma_f32_32x32x16_bf16(w2f0, qa, c2, 0, 0, 0);
        a2 = __builtin_amdgcn_mfma_f32_32x32x16_bf16(w2f1, qb, a2, 0, 0, 0);
        accum(a2);
    });
    flush(1);
    gbarrier(cnt, 2 * NBLK, tid);
    derive(1, g2, be2, b2);

    bf16x8 w3f0, w3f1;
    build_wf(W3, w3f0, w3f1);
    f32x16 c3;
    #pragma unroll
    for (int i = 0; i < 16; ++i) {
        int p = (i & 3) + 8 * (i >> 2) + 4 * h;
        c2[i] = s_e[p];
        c3[i] = b3[p];
    }

    // ---------------- Phase 3: z3 stats ----------------
    zero_acc();
    run2([&](int t) {
        bf16x8 xf = loadxb(t);
        f32x16 a1 = __builtin_amdgcn_mfma_f32_32x32x16_bf16(w1f, xf, c1, 0, 0, 0);
        bf16x8 qa, qb;
        #pragma unroll
        for (int j = 0; j < 8; ++j) {
            qa[j] = (__bf16)fmaxf(a1[j], 0.f);
            qb[j] = (__bf16)fmaxf(a1[8 + j], 0.f);
        }
        f32x16 a2 = __builtin_amdgcn_mfma_f32_32x32x16_bf16(w2f0, qa, c2, 0, 0, 0);
        a2 = __builtin_amdgcn_mfma_f32_32x32x16_bf16(w2f1, qb, a2, 0, 0, 0);
        bf16x8 pa, pb;
        #pragma unroll
        for (int j = 0; j < 8; ++j) {
            pa[j] = (__bf16)fmaxf(a2[j], 0.f);
            pb[j] = (__bf16)fmaxf(a2[8 + j], 0.f);
        }
        f32x16 a3 = __builtin_amdgcn_mfma_f32_32x32x16_bf16(w3f0, pa, c3, 0, 0, 0);
        a3 = __builtin_amdgcn_mfma_f32_32x32x16_bf16(w3f1, pb, a3, 0, 0, 0);
        accum(a3);
    });
    flush(2);
    gbarrier(cnt, 3 * NBLK, tid);
    derive(2, g3, be3, b3);

    float w4c[16];
    #pragma unroll
    for (int i = 0; i < 16; ++i) {
        int p = (i & 3) + 8 * (i >> 2) + 4 * h;
        c3[i]  = s_e[p];
        w4c[i] = W4[p] * s_a[p];
    }
    const float b4v = b4[0];

    // ---------------- Phase 4: output ----------------
    run2([&](int t) {
        bf16x8 xf = loadxb(t);
        f32x16 a1 = __builtin_amdgcn_mfma_f32_32x32x16_bf16(w1f, xf, c1, 0, 0, 0);
        bf16x8 qa, qb;
        #pragma unroll
        for (int j = 0; j < 8; ++j) {
            qa[j] = (__bf16)fmaxf(a1[j], 0.f);
            qb[j] = (__bf16)fmaxf(a1[8 + j], 0.f);
        }
        f32x16 a2 = __builtin_amdgcn_mfma_f32_32x32x16_bf16(w2f0, qa, c2, 0, 0, 0);
        a2 = __builtin_amdgcn_mfma_f32_32x32x16_bf16(w2f1, qb, a2, 0, 0, 0);
        bf16x8 pa, pb;
        #pragma unroll
        for (int j = 0; j < 8; ++j) {
            pa[j] = (__bf16)fmaxf(a2[j], 0.f);
            pb[j] = (__bf16)fmaxf(a2[8 + j], 0.f);
        }
        f32x16 a3 = __builtin_amdgcn_mfma_f32_32x32x16_bf16(w3f0, pa, c3, 0, 0, 0);
        a3 = __builtin_amdgcn_mfma_f32_32x32x16_bf16(w3f1, pb, a3, 0, 0, 0);
        float o = 0.f;
        #pragma unroll
        for (int i = 0; i < 16; ++i) o = fmaf(w4c[i], fmaxf(a3[i], 0.f), o);
        o += __shfl_xor(o, 32);
        if (h == 0) out[(t << 5) + ml] = o + b4v;
    });
}

extern "C" void kernel_launch(void* const* d_in, const int* in_sizes, int n_in,
                              void* d_out, int out_size, void* d_ws, size_t ws_size,
                              hipStream_t stream) {
    const float* x   = (const float*)d_in[0];
    const float* W1  = (const float*)d_in[1];
    const float* b1  = (const float*)d_in[2];
    const float* g1  = (const float*)d_in[3];
    const float* be1 = (const float*)d_in[4];
    const float* W2  = (const float*)d_in[5];
    const float* b2  = (const float*)d_in[6];
    const float* g2  = (const float*)d_in[7];
    const float* be2 = (const float*)d_in[8];
    const float* W3  = (const float*)d_in[9];
    const float* b3  = (const float*)d_in[10];
    const float* g3  = (const float*)d_in[11];
    const float* be3 = (const float*)d_in[12];
    const float* W4  = (const float*)d_in[13];
    const float* b4  = (const float*)d_in[14];
    float* out = (float*)d_out;
    int N = in_sizes[0] / 16;

    __bf16* xb   = (__bf16*)d_ws;
    char* ctrl   = (char*)d_ws + (size_t)N * 32;
    float* stats = (float*)ctrl;
    unsigned* cnt = (unsigned*)(ctrl + 192 * sizeof(float));

    hipMemsetAsync(ctrl, 0, 1024, stream);

    k_all<<<NBLK, NTHR, 0, stream>>>(x, xb, W1, b1, g1, be1, W2, b2, g2, be2,
                                     W3, b3, g3, be3, W4, b4, stats, cnt, out, N);
}

// Round 5
// 345.947 us; speedup vs baseline: 1.6370x; 1.6370x over previous
//
#include <hip/hip_runtime.h>

#define EPS 1e-5f
#define NTHR 256
#define NBLK 2048
#define NSLOT 8

typedef __bf16 bf16x8 __attribute__((ext_vector_type(8)));
typedef float f32x16 __attribute__((ext_vector_type(16)));

// d_ws layout:
//   [0, N*32)                 bf16 x, tile-major MFMA B-frag order:
//                             xb[(t*64+lane)*8 .. +8)
//   [N*32, +3*NSLOT*64*4)     stats slots: layer L: stats[L*NSLOT*64+slot*64+idx]
//                             idx 0..31 = sum(z_L), 32..63 = sum(z_L^2)
//
// 32x32x16 bf16 MFMA layouts (m74/m101-verified):
//   C/D: col=lane&31 (data row), row p=(reg&3)+8*(reg>>2)+4h, h=lane>>5
//   A/B: m|n=lane&31, k=8h+j
// Acc regs 0..7 / 8..15 feed the next layer's B-frag; next-layer weights use
// columns permuted by phi(K)=(j&3)+8*(j>>2)+4h+16*kh (involution). BN scale
// a>0 folds into next-layer weight columns; shift e=b-mu+be/a folds into the
// accumulator init.
//
// Round-5 change: software-pipelined grid-stride loop (prefetch depth = one
// 2-tile pair ahead) so iteration i+1's global loads issue before iteration
// i's dependent MFMA chains — round 4 showed zero inter-iteration overlap
// (VALUBusy 9%, MfmaUtil 3%, HBM 7%: all idle, pure latency).

template<int DEPTH>
__global__ __launch_bounds__(NTHR) void k_fwd(
    const float* __restrict__ x, __bf16* __restrict__ xb,
    const float* __restrict__ W1, const float* __restrict__ b1,
    const float* __restrict__ g1, const float* __restrict__ be1,
    const float* __restrict__ W2, const float* __restrict__ b2,
    const float* __restrict__ g2, const float* __restrict__ be2,
    const float* __restrict__ W3, const float* __restrict__ b3,
    const float* __restrict__ g3, const float* __restrict__ be3,
    const float* __restrict__ W4, const float* __restrict__ b4,
    float* __restrict__ stats, float* __restrict__ out, int N)
{
    constexpr bool STATS = (DEPTH < 4);
    __shared__ float s_stat[3][64];
    __shared__ float s_a[3][32];
    __shared__ float s_e[3][32];
    __shared__ float s_b[64];

    const int tid = threadIdx.x;
    const float invN = 1.0f / (float)N;

    if (tid < 64) {
        for (int L = 0; L < DEPTH - 1; ++L) {
            float a = 0.f;
            #pragma unroll
            for (int s = 0; s < NSLOT; ++s) a += stats[L * (NSLOT * 64) + s * 64 + tid];
            s_stat[L][tid] = a;
        }
    }
    __syncthreads();
    if (tid < 32) {
        const float* gs[3]  = {g1, g2, g3};
        const float* bes[3] = {be1, be2, be3};
        const float* bs[3]  = {b1, b2, b3};
        for (int L = 0; L < DEPTH - 1; ++L) {
            float mu = s_stat[L][tid] * invN;
            float v  = s_stat[L][32 + tid] * invN - mu * mu;
            float a  = gs[L][tid] * rsqrtf(v + EPS);
            s_a[L][tid] = a;
            s_e[L][tid] = bs[L][tid] - mu + bes[L][tid] / a;
        }
    }
    if (STATS && tid < 64) s_b[tid] = 0.f;
    __syncthreads();

    const int lane = tid & 63;
    const int h = lane >> 5;
    const int ml = lane & 31;

    bf16x8 w1f;
    {
        const float* p = W1 + ml * 16 + h * 8;
        #pragma unroll
        for (int j = 0; j < 8; ++j) w1f[j] = (__bf16)p[j];
    }
    bf16x8 w2f0 = {}, w2f1 = {}, w3f0 = {}, w3f1 = {};
    if (DEPTH >= 2) {
        #pragma unroll
        for (int kh = 0; kh < 2; ++kh)
            #pragma unroll
            for (int j = 0; j < 8; ++j) {
                int pk = (j & 3) + 8 * (j >> 2) + 4 * h + 16 * kh;
                float v = W2[ml * 32 + pk] * s_a[0][pk];
                if (kh == 0) w2f0[j] = (__bf16)v; else w2f1[j] = (__bf16)v;
            }
    }
    if (DEPTH >= 3) {
        #pragma unroll
        for (int kh = 0; kh < 2; ++kh)
            #pragma unroll
            for (int j = 0; j < 8; ++j) {
                int pk = (j & 3) + 8 * (j >> 2) + 4 * h + 16 * kh;
                float v = W3[ml * 32 + pk] * s_a[1][pk];
                if (kh == 0) w3f0[j] = (__bf16)v; else w3f1[j] = (__bf16)v;
            }
    }

    f32x16 c1, c2 = {}, c3 = {};
    float w4c[16];
    #pragma unroll
    for (int i = 0; i < 16; ++i) {
        int p = (i & 3) + 8 * (i >> 2) + 4 * h;
        c1[i] = (DEPTH == 1) ? b1[p] : s_e[0][p];
        if (DEPTH >= 2) c2[i] = (DEPTH == 2) ? b2[p] : s_e[1][p];
        if (DEPTH >= 3) c3[i] = (DEPTH == 3) ? b3[p] : s_e[2][p];
        if (DEPTH == 4) w4c[i] = W4[p] * s_a[2][p]; else w4c[i] = 0.f;
    }
    const float b4v = (DEPTH == 4) ? b4[0] : 0.f;

    const int ntiles = N >> 5;                    // 65536
    const int nwaves = NBLK * (NTHR / 64);        // 8192
    const int gwave  = blockIdx.x * (NTHR / 64) + (tid >> 6);
    const int K      = ntiles / nwaves;           // 8 (exact for this problem)

    float sums[16], sqs[16];
    #pragma unroll
    for (int i = 0; i < 16; ++i) { sums[i] = 0.f; sqs[i] = 0.f; }

    auto tile = [&](int t, bf16x8 xf) {
        f32x16 a1 = __builtin_amdgcn_mfma_f32_32x32x16_bf16(w1f, xf, c1, 0, 0, 0);
        if (DEPTH == 1) {
            #pragma unroll
            for (int i = 0; i < 16; ++i) { sums[i] += a1[i]; sqs[i] = fmaf(a1[i], a1[i], sqs[i]); }
            return;
        }
        bf16x8 qa, qb;
        #pragma unroll
        for (int j = 0; j < 8; ++j) {
            qa[j] = (__bf16)fmaxf(a1[j], 0.f);
            qb[j] = (__bf16)fmaxf(a1[8 + j], 0.f);
        }
        f32x16 a2 = __builtin_amdgcn_mfma_f32_32x32x16_bf16(w2f0, qa, c2, 0, 0, 0);
        a2 = __builtin_amdgcn_mfma_f32_32x32x16_bf16(w2f1, qb, a2, 0, 0, 0);
        if (DEPTH == 2) {
            #pragma unroll
            for (int i = 0; i < 16; ++i) { sums[i] += a2[i]; sqs[i] = fmaf(a2[i], a2[i], sqs[i]); }
            return;
        }
        bf16x8 pa, pb;
        #pragma unroll
        for (int j = 0; j < 8; ++j) {
            pa[j] = (__bf16)fmaxf(a2[j], 0.f);
            pb[j] = (__bf16)fmaxf(a2[8 + j], 0.f);
        }
        f32x16 a3 = __builtin_amdgcn_mfma_f32_32x32x16_bf16(w3f0, pa, c3, 0, 0, 0);
        a3 = __builtin_amdgcn_mfma_f32_32x32x16_bf16(w3f1, pb, a3, 0, 0, 0);
        if (DEPTH == 3) {
            #pragma unroll
            for (int i = 0; i < 16; ++i) { sums[i] += a3[i]; sqs[i] = fmaf(a3[i], a3[i], sqs[i]); }
            return;
        }
        float o = 0.f;
        #pragma unroll
        for (int i = 0; i < 16; ++i) o = fmaf(w4c[i], fmaxf(a3[i], 0.f), o);
        o += __shfl_xor(o, 32);
        if (h == 0) out[(t << 5) + ml] = o + b4v;
    };

    if (DEPTH == 1) {
        // raw fp32 loads, software-pipelined one pair ahead
        auto loadraw = [&](int t, float4& u0, float4& u1) {
            const float4* xp = (const float4*)(x + (size_t)((t << 5) + ml) * 16 + h * 8);
            u0 = xp[0]; u1 = xp[1];
        };
        auto cvt = [&](const float4& u0, const float4& u1) -> bf16x8 {
            bf16x8 xf;
            xf[0] = (__bf16)u0.x; xf[1] = (__bf16)u0.y; xf[2] = (__bf16)u0.z; xf[3] = (__bf16)u0.w;
            xf[4] = (__bf16)u1.x; xf[5] = (__bf16)u1.y; xf[6] = (__bf16)u1.z; xf[7] = (__bf16)u1.w;
            return xf;
        };
        float4 a0, a1v, b0, b1v, p0, p1, q0, q1;
        loadraw(gwave, a0, a1v);
        loadraw(gwave + nwaves, b0, b1v);
        for (int i = 0; i < K; i += 2) {
            int t0 = gwave + i * nwaves;
            if (i + 2 < K) {
                loadraw(t0 + 2 * nwaves, p0, p1);
                loadraw(t0 + 3 * nwaves, q0, q1);
            }
            bf16x8 xf0 = cvt(a0, a1v);
            *(bf16x8*)(xb + ((size_t)t0 * 64 + lane) * 8) = xf0;
            bf16x8 xf1 = cvt(b0, b1v);
            *(bf16x8*)(xb + ((size_t)(t0 + nwaves) * 64 + lane) * 8) = xf1;
            tile(t0, xf0);
            tile(t0 + nwaves, xf1);
            a0 = p0; a1v = p1; b0 = q0; b1v = q1;
        }
    } else {
        auto loadxb = [&](int t) -> bf16x8 {
            return *(const bf16x8*)(xb + ((size_t)t * 64 + lane) * 8);
        };
        bf16x8 xa = loadxb(gwave);
        bf16x8 xbv = loadxb(gwave + nwaves);
        for (int i = 0; i < K; i += 2) {
            int t0 = gwave + i * nwaves;
            bf16x8 xc = {}, xd = {};
            if (i + 2 < K) {
                xc = loadxb(t0 + 2 * nwaves);
                xd = loadxb(t0 + 3 * nwaves);
            }
            tile(t0, xa);
            tile(t0 + nwaves, xbv);
            xa = xc; xbv = xd;
        }
    }

    if (STATS) {
        #pragma unroll
        for (int i = 0; i < 16; ++i) {
            float s = sums[i], q = sqs[i];
            #pragma unroll
            for (int d = 1; d <= 16; d <<= 1) {
                s += __shfl_xor(s, d);
                q += __shfl_xor(q, d);
            }
            if (ml == 0) {
                int p = (i & 3) + 8 * (i >> 2) + 4 * h;
                atomicAdd(&s_b[p], s);
                atomicAdd(&s_b[32 + p], q);
            }
        }
        __syncthreads();
        if (tid < 64) {
            int L = DEPTH - 1;
            atomicAdd(&stats[L * (NSLOT * 64) + (blockIdx.x & (NSLOT - 1)) * 64 + tid], s_b[tid]);
        }
    }
}

extern "C" void kernel_launch(void* const* d_in, const int* in_sizes, int n_in,
                              void* d_out, int out_size, void* d_ws, size_t ws_size,
                              hipStream_t stream) {
    const float* x   = (const float*)d_in[0];
    const float* W1  = (const float*)d_in[1];
    const float* b1  = (const float*)d_in[2];
    const float* g1  = (const float*)d_in[3];
    const float* be1 = (const float*)d_in[4];
    const float* W2  = (const float*)d_in[5];
    const float* b2  = (const float*)d_in[6];
    const float* g2  = (const float*)d_in[7];
    const float* be2 = (const float*)d_in[8];
    const float* W3  = (const float*)d_in[9];
    const float* b3  = (const float*)d_in[10];
    const float* g3  = (const float*)d_in[11];
    const float* be3 = (const float*)d_in[12];
    const float* W4  = (const float*)d_in[13];
    const float* b4  = (const float*)d_in[14];
    float* out = (float*)d_out;
    int N = in_sizes[0] / 16;

    __bf16* xb   = (__bf16*)d_ws;
    float* stats = (float*)((char*)d_ws + (size_t)N * 32);

    hipMemsetAsync(stats, 0, 3 * NSLOT * 64 * sizeof(float), stream);

    k_fwd<1><<<NBLK, NTHR, 0, stream>>>(x, xb, W1, b1, g1, be1, W2, b2, g2, be2, W3, b3, g3, be3, W4, b4, stats, out, N);
    k_fwd<2><<<NBLK, NTHR, 0, stream>>>(x, xb, W1, b1, g1, be1, W2, b2, g2, be2, W3, b3, g3, be3, W4, b4, stats, out, N);
    k_fwd<3><<<NBLK, NTHR, 0, stream>>>(x, xb, W1, b1, g1, be1, W2, b2, g2, be2, W3, b3, g3, be3, W4, b4, stats, out, N);
    k_fwd<4><<<NBLK, NTHR, 0, stream>>>(x, xb, W1, b1, g1, be1, W2, b2, g2, be2, W3, b3, g3, be3, W4, b4, stats, out, N);
}

// Round 6
// 330.124 us; speedup vs baseline: 1.7154x; 1.0479x over previous
//
#include <hip/hip_runtime.h>

#define EPS 1e-5f
#define NTHR 256
#define NBLK 1024
#define NSLOT 8

typedef __bf16 bf16x8 __attribute__((ext_vector_type(8)));
typedef float f32x16 __attribute__((ext_vector_type(16)));

// d_ws layout:
//   [0, N*32)                 bf16 x, tile-major MFMA B-frag order:
//                             xb[(t*64+lane)*8 .. +8)
//   [N*32, +3*NSLOT*64*4)     stats slots: layer L: stats[L*NSLOT*64+slot*64+idx]
//                             idx 0..31 = sum(z_L), 32..63 = sum(z_L^2)
//
// 32x32x16 bf16 MFMA layouts (m74/m101-verified):
//   C/D: col=lane&31 (data row), row p=(reg&3)+8*(reg>>2)+4h, h=lane>>5
//   A/B: m|n=lane&31, k=8h+j
// Acc regs 0..7 / 8..15 feed the next layer's B-frag; next-layer weights use
// columns permuted by phi(K)=(j&3)+8*(j>>2)+4h+16*kh (involution). BN scale
// a>0 folds into next-layer weight columns; shift e=b-mu+be/a folds into the
// accumulator init.
//
// Round-6: hand-interleaved 2-tile chains (true source-order ILP=2 through the
// dependent MFMA->repack->MFMA pipeline) + 4-deep register prefetch ring.
// R5 evidence: compiler does NOT interleave separately-written tile bodies.

template<int DEPTH>
__global__ __launch_bounds__(NTHR) void k_fwd(
    const float* __restrict__ x, __bf16* __restrict__ xb,
    const float* __restrict__ W1, const float* __restrict__ b1,
    const float* __restrict__ g1, const float* __restrict__ be1,
    const float* __restrict__ W2, const float* __restrict__ b2,
    const float* __restrict__ g2, const float* __restrict__ be2,
    const float* __restrict__ W3, const float* __restrict__ b3,
    const float* __restrict__ g3, const float* __restrict__ be3,
    const float* __restrict__ W4, const float* __restrict__ b4,
    float* __restrict__ stats, float* __restrict__ out, int N)
{
    constexpr bool STATS = (DEPTH < 4);
    __shared__ float s_stat[3][64];
    __shared__ float s_a[3][32];
    __shared__ float s_e[3][32];
    __shared__ float s_b[64];

    const int tid = threadIdx.x;
    const float invN = 1.0f / (float)N;

    if (tid < 64) {
        for (int L = 0; L < DEPTH - 1; ++L) {
            float a = 0.f;
            #pragma unroll
            for (int s = 0; s < NSLOT; ++s) a += stats[L * (NSLOT * 64) + s * 64 + tid];
            s_stat[L][tid] = a;
        }
    }
    __syncthreads();
    if (tid < 32) {
        const float* gs[3]  = {g1, g2, g3};
        const float* bes[3] = {be1, be2, be3};
        const float* bs[3]  = {b1, b2, b3};
        for (int L = 0; L < DEPTH - 1; ++L) {
            float mu = s_stat[L][tid] * invN;
            float v  = s_stat[L][32 + tid] * invN - mu * mu;
            float a  = gs[L][tid] * rsqrtf(v + EPS);
            s_a[L][tid] = a;
            s_e[L][tid] = bs[L][tid] - mu + bes[L][tid] / a;
        }
    }
    if (STATS && tid < 64) s_b[tid] = 0.f;
    __syncthreads();

    const int lane = tid & 63;
    const int h = lane >> 5;
    const int ml = lane & 31;

    bf16x8 w1f;
    {
        const float* p = W1 + ml * 16 + h * 8;
        #pragma unroll
        for (int j = 0; j < 8; ++j) w1f[j] = (__bf16)p[j];
    }
    bf16x8 w2f0 = {}, w2f1 = {}, w3f0 = {}, w3f1 = {};
    if (DEPTH >= 2) {
        #pragma unroll
        for (int kh = 0; kh < 2; ++kh)
            #pragma unroll
            for (int j = 0; j < 8; ++j) {
                int pk = (j & 3) + 8 * (j >> 2) + 4 * h + 16 * kh;
                float v = W2[ml * 32 + pk] * s_a[0][pk];
                if (kh == 0) w2f0[j] = (__bf16)v; else w2f1[j] = (__bf16)v;
            }
    }
    if (DEPTH >= 3) {
        #pragma unroll
        for (int kh = 0; kh < 2; ++kh)
            #pragma unroll
            for (int j = 0; j < 8; ++j) {
                int pk = (j & 3) + 8 * (j >> 2) + 4 * h + 16 * kh;
                float v = W3[ml * 32 + pk] * s_a[1][pk];
                if (kh == 0) w3f0[j] = (__bf16)v; else w3f1[j] = (__bf16)v;
            }
    }

    f32x16 c1, c2 = {}, c3 = {};
    float w4c[16];
    #pragma unroll
    for (int i = 0; i < 16; ++i) {
        int p = (i & 3) + 8 * (i >> 2) + 4 * h;
        c1[i] = (DEPTH == 1) ? b1[p] : s_e[0][p];
        if (DEPTH >= 2) c2[i] = (DEPTH == 2) ? b2[p] : s_e[1][p];
        if (DEPTH >= 3) c3[i] = (DEPTH == 3) ? b3[p] : s_e[2][p];
        if (DEPTH == 4) w4c[i] = W4[p] * s_a[2][p]; else w4c[i] = 0.f;
    }
    const float b4v = (DEPTH == 4) ? b4[0] : 0.f;

    const int ntiles = N >> 5;                    // 65536
    const int nwaves = NBLK * (NTHR / 64);        // 4096
    const int gwave  = blockIdx.x * (NTHR / 64) + (tid >> 6);
    const int K      = ntiles / nwaves;           // 16 (exact here)

    float sums[16], sqs[16];
    #pragma unroll
    for (int i = 0; i < 16; ++i) { sums[i] = 0.f; sqs[i] = 0.f; }

    // dual-tile accumulate: one add + two fma per element pair
    auto accum2 = [&](const f32x16& A, const f32x16& B) {
        #pragma unroll
        for (int i = 0; i < 16; ++i) {
            sums[i] += A[i] + B[i];
            sqs[i]  = fmaf(A[i], A[i], fmaf(B[i], B[i], sqs[i]));
        }
    };
    auto accum1 = [&](const f32x16& A) {
        #pragma unroll
        for (int i = 0; i < 16; ++i) { sums[i] += A[i]; sqs[i] = fmaf(A[i], A[i], sqs[i]); }
    };
    // relu in f32 then pack to bf16 (relu∘round == round∘relu)
    auto rp = [&](const f32x16& a, bf16x8& lo, bf16x8& hi) {
        #pragma unroll
        for (int j = 0; j < 8; ++j) {
            lo[j] = (__bf16)fmaxf(a[j], 0.f);
            hi[j] = (__bf16)fmaxf(a[8 + j], 0.f);
        }
    };

    // hand-interleaved pair of independent tiles t0,t1 (xf0,xf1 preloaded)
    auto pair = [&](int t0, int t1, bf16x8 xf0, bf16x8 xf1) {
        f32x16 A1 = __builtin_amdgcn_mfma_f32_32x32x16_bf16(w1f, xf0, c1, 0, 0, 0);
        f32x16 B1 = __builtin_amdgcn_mfma_f32_32x32x16_bf16(w1f, xf1, c1, 0, 0, 0);
        if (DEPTH == 1) { accum2(A1, B1); return; }
        bf16x8 qa0, qb0, qa1, qb1;
        rp(A1, qa0, qb0);
        rp(B1, qa1, qb1);
        f32x16 A2 = __builtin_amdgcn_mfma_f32_32x32x16_bf16(w2f0, qa0, c2, 0, 0, 0);
        f32x16 B2 = __builtin_amdgcn_mfma_f32_32x32x16_bf16(w2f0, qa1, c2, 0, 0, 0);
        A2 = __builtin_amdgcn_mfma_f32_32x32x16_bf16(w2f1, qb0, A2, 0, 0, 0);
        B2 = __builtin_amdgcn_mfma_f32_32x32x16_bf16(w2f1, qb1, B2, 0, 0, 0);
        if (DEPTH == 2) { accum2(A2, B2); return; }
        rp(A2, qa0, qb0);
        rp(B2, qa1, qb1);
        f32x16 A3 = __builtin_amdgcn_mfma_f32_32x32x16_bf16(w3f0, qa0, c3, 0, 0, 0);
        f32x16 B3 = __builtin_amdgcn_mfma_f32_32x32x16_bf16(w3f0, qa1, c3, 0, 0, 0);
        A3 = __builtin_amdgcn_mfma_f32_32x32x16_bf16(w3f1, qb0, A3, 0, 0, 0);
        B3 = __builtin_amdgcn_mfma_f32_32x32x16_bf16(w3f1, qb1, B3, 0, 0, 0);
        if (DEPTH == 3) { accum2(A3, B3); return; }
        float oA = 0.f, oB = 0.f;
        #pragma unroll
        for (int i = 0; i < 16; ++i) {
            oA = fmaf(w4c[i], fmaxf(A3[i], 0.f), oA);
            oB = fmaf(w4c[i], fmaxf(B3[i], 0.f), oB);
        }
        oA += __shfl_xor(oA, 32);
        oB += __shfl_xor(oB, 32);
        if (h == 0) {
            out[(t0 << 5) + ml] = oA + b4v;
            out[(t1 << 5) + ml] = oB + b4v;
        }
    };

    auto tile1 = [&](int t, bf16x8 xf) {
        f32x16 A1 = __builtin_amdgcn_mfma_f32_32x32x16_bf16(w1f, xf, c1, 0, 0, 0);
        if (DEPTH == 1) { accum1(A1); return; }
        bf16x8 qa, qb;
        rp(A1, qa, qb);
        f32x16 A2 = __builtin_amdgcn_mfma_f32_32x32x16_bf16(w2f0, qa, c2, 0, 0, 0);
        A2 = __builtin_amdgcn_mfma_f32_32x32x16_bf16(w2f1, qb, A2, 0, 0, 0);
        if (DEPTH == 2) { accum1(A2); return; }
        rp(A2, qa, qb);
        f32x16 A3 = __builtin_amdgcn_mfma_f32_32x32x16_bf16(w3f0, qa, c3, 0, 0, 0);
        A3 = __builtin_amdgcn_mfma_f32_32x32x16_bf16(w3f1, qb, A3, 0, 0, 0);
        if (DEPTH == 3) { accum1(A3); return; }
        float o = 0.f;
        #pragma unroll
        for (int i = 0; i < 16; ++i) o = fmaf(w4c[i], fmaxf(A3[i], 0.f), o);
        o += __shfl_xor(o, 32);
        if (h == 0) out[(t << 5) + ml] = o + b4v;
    };

    if (DEPTH == 1) {
        // fp32 source loads, one pair prefetched ahead, interleaved compute
        auto loadraw = [&](int t, float4& u0, float4& u1) {
            const float4* xp = (const float4*)(x + (size_t)((t << 5) + ml) * 16 + h * 8);
            u0 = xp[0]; u1 = xp[1];
        };
        auto cvt = [&](const float4& u0, const float4& u1) -> bf16x8 {
            bf16x8 xf;
            xf[0] = (__bf16)u0.x; xf[1] = (__bf16)u0.y; xf[2] = (__bf16)u0.z; xf[3] = (__bf16)u0.w;
            xf[4] = (__bf16)u1.x; xf[5] = (__bf16)u1.y; xf[6] = (__bf16)u1.z; xf[7] = (__bf16)u1.w;
            return xf;
        };
        float4 a0, a1v, b0, b1v, p0, p1, q0, q1;
        int t = gwave;
        loadraw(t, a0, a1v);
        loadraw(t + nwaves, b0, b1v);
        for (int i = 0; i < K; i += 2) {
            int t0 = t + i * nwaves;
            if (i + 3 < K) {
                loadraw(t0 + 2 * nwaves, p0, p1);
                loadraw(t0 + 3 * nwaves, q0, q1);
            }
            bf16x8 xf0 = cvt(a0, a1v);
            bf16x8 xf1 = cvt(b0, b1v);
            *(bf16x8*)(xb + ((size_t)t0 * 64 + lane) * 8) = xf0;
            *(bf16x8*)(xb + ((size_t)(t0 + nwaves) * 64 + lane) * 8) = xf1;
            pair(t0, t0 + nwaves, xf0, xf1);
            a0 = p0; a1v = p1; b0 = q0; b1v = q1;
        }
        for (int t2 = t + K * nwaves; t2 < ntiles; t2 += nwaves) {  // safety tail
            float4 u0, u1;
            loadraw(t2, u0, u1);
            bf16x8 xf = cvt(u0, u1);
            *(bf16x8*)(xb + ((size_t)t2 * 64 + lane) * 8) = xf;
            tile1(t2, xf);
        }
    } else {
        auto loadxb = [&](int t) -> bf16x8 {
            return *(const bf16x8*)(xb + ((size_t)t * 64 + lane) * 8);
        };
        // 4-deep register ring
        bf16x8 r0 = loadxb(gwave);
        bf16x8 r1 = loadxb(gwave + nwaves);
        bf16x8 r2 = loadxb(gwave + 2 * nwaves);
        bf16x8 r3 = loadxb(gwave + 3 * nwaves);
        for (int i = 0; i < K; i += 2) {
            int t0 = gwave + i * nwaves;
            bf16x8 n0 = {}, n1 = {};
            if (i + 5 < K) {
                n0 = loadxb(t0 + 4 * nwaves);
                n1 = loadxb(t0 + 5 * nwaves);
            }
            pair(t0, t0 + nwaves, r0, r1);
            r0 = r2; r1 = r3; r2 = n0; r3 = n1;
        }
        for (int t2 = gwave + K * nwaves; t2 < ntiles; t2 += nwaves)  // safety tail
            tile1(t2, loadxb(t2));
    }

    if (STATS) {
        #pragma unroll
        for (int i = 0; i < 16; ++i) {
            float s = sums[i], q = sqs[i];
            #pragma unroll
            for (int d = 1; d <= 16; d <<= 1) {
                s += __shfl_xor(s, d);
                q += __shfl_xor(q, d);
            }
            if (ml == 0) {
                int p = (i & 3) + 8 * (i >> 2) + 4 * h;
                atomicAdd(&s_b[p], s);
                atomicAdd(&s_b[32 + p], q);
            }
        }
        __syncthreads();
        if (tid < 64) {
            int L = DEPTH - 1;
            atomicAdd(&stats[L * (NSLOT * 64) + (blockIdx.x & (NSLOT - 1)) * 64 + tid], s_b[tid]);
        }
    }
}

extern "C" void kernel_launch(void* const* d_in, const int* in_sizes, int n_in,
                              void* d_out, int out_size, void* d_ws, size_t ws_size,
                              hipStream_t stream) {
    const float* x   = (const float*)d_in[0];
    const float* W1  = (const float*)d_in[1];
    const float* b1  = (const float*)d_in[2];
    const float* g1  = (const float*)d_in[3];
    const float* be1 = (const float*)d_in[4];
    const float* W2  = (const float*)d_in[5];
    const float* b2  = (const float*)d_in[6];
    const float* g2  = (const float*)d_in[7];
    const float* be2 = (const float*)d_in[8];
    const float* W3  = (const float*)d_in[9];
    const float* b3  = (const float*)d_in[10];
    const float* g3  = (const float*)d_in[11];
    const float* be3 = (const float*)d_in[12];
    const float* W4  = (const float*)d_in[13];
    const float* b4  = (const float*)d_in[14];
    float* out = (float*)d_out;
    int N = in_sizes[0] / 16;

    __bf16* xb   = (__bf16*)d_ws;
    float* stats = (float*)((char*)d_ws + (size_t)N * 32);

    hipMemsetAsync(stats, 0, 3 * NSLOT * 64 * sizeof(float), stream);

    k_fwd<1><<<NBLK, NTHR, 0, stream>>>(x, xb, W1, b1, g1, be1, W2, b2, g2, be2, W3, b3, g3, be3, W4, b4, stats, out, N);
    k_fwd<2><<<NBLK, NTHR, 0, stream>>>(x, xb, W1, b1, g1, be1, W2, b2, g2, be2, W3, b3, g3, be3, W4, b4, stats, out, N);
    k_fwd<3><<<NBLK, NTHR, 0, stream>>>(x, xb, W1, b1, g1, be1, W2, b2, g2, be2, W3, b3, g3, be3, W4, b4, stats, out, N);
    k_fwd<4><<<NBLK, NTHR, 0, stream>>>(x, xb, W1, b1, g1, be1, W2, b2, g2, be2, W3, b3, g3, be3, W4, b4, stats, out, N);
}